// Round 9
// baseline (55.587 us; speedup 1.0000x reference)
//
#include <hip/hip_runtime.h>

// Problem constants (match reference setup_inputs)
#define NBAGS 64
#define D 512          // feature dim (floats)
#define D4 128         // feature dim in float4
#define NCH 2048       // uniform slabs: exactly 8 blocks/CU on 256 CUs (32 waves/CU)

// Block g owns rows [g*tt/NCH, (g+1)*tt/NCH) — EXACTLY uniform work per block
// (64 rows = 128 KiB for tt=131072), independent of bag boundaries.
// Slabs crossing bag boundaries split into sub-segments; each segment's
// column-sum is scaled by 1/count and atomicAdd-ed into out (zeroed by memset).
// Bag prefix sums are computed lane-parallel in wave 0 and shared via LDS.

__device__ __forceinline__ int lane_incl_scan(int v, int lane) {
#pragma unroll
    for (int off = 1; off < 64; off <<= 1) {
        int o = __shfl_up(v, off, 64);
        if (lane >= off) v += o;
    }
    return v;
}

// block = 256 threads. thread t: float4 column (t & 127), row parity (t >> 7).
__global__ __launch_bounds__(256, 8) void
agg_slab_kernel(const float* __restrict__ samples,
                const int* __restrict__ counts,
                float* __restrict__ out, int tt) {
    __shared__ int s_ps[NBAGS + 1];   // row prefix sums: ps[0]=0 .. ps[64]=tt
    __shared__ float4 s_red[D4];      // half-combine buffer

    const int t = threadIdx.x;
    const int g = blockIdx.x;

    if (t == 0) s_ps[0] = 0;
    if (t < 64) {
        const int c = counts[t];
        s_ps[t + 1] = lane_incl_scan(c, t);   // inclusive scan, lane t = bag t
    }
    __syncthreads();

    // Slab bounds (g*tt <= 2047*131072 < 2^31: int32 safe).
    const int r0 = (int)(((long long)g * tt) / NCH);
    const int r1 = (int)(((long long)(g + 1) * tt) / NCH);

    const int col  = t & (D4 - 1);
    const int half = t >> 7;
    const float4* __restrict__ src = (const float4*)samples;  // row stride D4

    // Find bag containing r0 (uniform across block; 6-step binary search).
    int k;
    {
        int lo = 0, hi = NBAGS;
        while (hi - lo > 1) {
            int mid = (lo + hi) >> 1;
            if (s_ps[mid] <= r0) lo = mid; else hi = mid;
        }
        k = lo;
    }

    int cur = r0;
    while (cur < r1) {
        const int bend = s_ps[k + 1];
        const int e    = (bend < r1) ? bend : r1;   // segment [cur, e) in bag k

        // 4 float4 loads in flight per thread (rows stride 2 within segment).
        float4 a0 = make_float4(0.f, 0.f, 0.f, 0.f);
        float4 a1 = make_float4(0.f, 0.f, 0.f, 0.f);
        int r = cur + half;
        for (; r + 6 < e; r += 8) {
            float4 v0 = src[(r    ) * D4 + col];
            float4 v1 = src[(r + 2) * D4 + col];
            float4 v2 = src[(r + 4) * D4 + col];
            float4 v3 = src[(r + 6) * D4 + col];
            a0.x += v0.x; a0.y += v0.y; a0.z += v0.z; a0.w += v0.w;
            a1.x += v1.x; a1.y += v1.y; a1.z += v1.z; a1.w += v1.w;
            a0.x += v2.x; a0.y += v2.y; a0.z += v2.z; a0.w += v2.w;
            a1.x += v3.x; a1.y += v3.y; a1.z += v3.z; a1.w += v3.w;
        }
        for (; r < e; r += 2) {
            float4 v = src[r * D4 + col];
            a0.x += v.x; a0.y += v.y; a0.z += v.z; a0.w += v.w;
        }
        a0.x += a1.x; a0.y += a1.y; a0.z += a1.z; a0.w += a1.w;

        // Combine the two row-parity halves; half 0 accumulates into out.
        if (half == 1) s_red[col] = a0;
        __syncthreads();
        if (half == 0) {
            float4 o = s_red[col];
            a0.x += o.x; a0.y += o.y; a0.z += o.z; a0.w += o.w;
            const float inv = 1.0f / (float)(s_ps[k + 1] - s_ps[k]);
            float* dst = out + k * D + col * 4;
            atomicAdd(dst + 0, a0.x * inv);
            atomicAdd(dst + 1, a0.y * inv);
            atomicAdd(dst + 2, a0.z * inv);
            atomicAdd(dst + 3, a0.w * inv);
        }
        __syncthreads();   // protect s_red before next segment reuses it
        cur = e;
        ++k;
    }
}

extern "C" void kernel_launch(void* const* d_in, const int* in_sizes, int n_in,
                              void* d_out, int out_size, void* d_ws, size_t ws_size,
                              hipStream_t stream) {
    const float* samples = (const float*)d_in[0];
    const int*   counts  = (const int*)d_in[1];   // harness converts int64 -> int32
    float*       out     = (float*)d_out;
    const int    tt      = in_sizes[0] / D;       // total rows (131072)

    // Zero the output accumulator (graph-capturable).
    hipMemsetAsync(out, 0, (size_t)out_size * sizeof(float), stream);
    agg_slab_kernel<<<NCH, 256, 0, stream>>>(samples, counts, out, tt);
}

// Round 10
// 53.801 us; speedup vs baseline: 1.0332x; 1.0332x over previous
//
#include <hip/hip_runtime.h>

// Problem constants (match reference setup_inputs)
#define NBAGS 64
#define D 512          // feature dim (floats)
#define D4 128         // feature dim in float4
#define NCH 1024       // uniform slabs: exactly 4 blocks/CU on 256 CUs

// Block g owns rows [g*tt/NCH, (g+1)*tt/NCH) — exactly uniform work per block
// (128 rows = 256 KiB), independent of bag boundaries. Slabs crossing bag
// boundaries split into sub-segments; each segment's column-sum is scaled by
// 1/count and atomicAdd-ed into out (zeroed by memset).
//
// Round-10 change (isolated): CONTIGUOUS per-wave-pair row runs + 8-deep ILP.
// Each segment [cur,e) splits into run A = [cur, cur+lenA) (waves 0/1, half=0)
// and run B = [cur+lenA, e) (waves 2/3, half=1). Threads sweep rows stride-1,
// 8 rows unrolled -> 8 float4 loads in flight per thread.

__device__ __forceinline__ int lane_incl_scan(int v, int lane) {
#pragma unroll
    for (int off = 1; off < 64; off <<= 1) {
        int o = __shfl_up(v, off, 64);
        if (lane >= off) v += o;
    }
    return v;
}

// block = 256 threads. thread t: float4 column (t & 127), row-run (t >> 7).
__global__ __launch_bounds__(256) void
agg_slab_kernel(const float* __restrict__ samples,
                const int* __restrict__ counts,
                float* __restrict__ out, int tt) {
    __shared__ int s_ps[NBAGS + 1];   // row prefix sums: ps[0]=0 .. ps[64]=tt
    __shared__ float4 s_red[D4];      // half-combine buffer

    const int t = threadIdx.x;
    const int g = blockIdx.x;

    if (t == 0) s_ps[0] = 0;
    if (t < 64) {
        const int c = counts[t];
        s_ps[t + 1] = lane_incl_scan(c, t);   // inclusive scan, lane t = bag t
    }
    __syncthreads();

    // Slab bounds (g*tt <= 1023*131072 < 2^31: int32 safe).
    const int r0 = (int)(((long long)g * tt) / NCH);
    const int r1 = (int)(((long long)(g + 1) * tt) / NCH);

    const int col  = t & (D4 - 1);
    const int half = t >> 7;
    const float4* __restrict__ src = (const float4*)samples;  // row stride D4

    // Find bag containing r0 (uniform across block; 6-step binary search).
    int k;
    {
        int lo = 0, hi = NBAGS;
        while (hi - lo > 1) {
            int mid = (lo + hi) >> 1;
            if (s_ps[mid] <= r0) lo = mid; else hi = mid;
        }
        k = lo;
    }

    int cur = r0;
    while (cur < r1) {
        const int bend = s_ps[k + 1];
        const int e    = (bend < r1) ? bend : r1;   // segment [cur, e) in bag k

        // Contiguous runs: half 0 -> [cur, cur+lenA), half 1 -> [cur+lenA, e).
        const int len  = e - cur;
        const int lenA = (len + 1) >> 1;
        int       r    = cur + half * lenA;
        const int rend = (half == 0) ? (cur + lenA) : e;

        float4 a0 = make_float4(0.f, 0.f, 0.f, 0.f);
        float4 a1 = make_float4(0.f, 0.f, 0.f, 0.f);
        // 8 float4 loads in flight per thread (rows stride 1 within run).
        for (; r + 7 < rend; r += 8) {
            float4 v0 = src[(r    ) * D4 + col];
            float4 v1 = src[(r + 1) * D4 + col];
            float4 v2 = src[(r + 2) * D4 + col];
            float4 v3 = src[(r + 3) * D4 + col];
            float4 v4 = src[(r + 4) * D4 + col];
            float4 v5 = src[(r + 5) * D4 + col];
            float4 v6 = src[(r + 6) * D4 + col];
            float4 v7 = src[(r + 7) * D4 + col];
            a0.x += v0.x; a0.y += v0.y; a0.z += v0.z; a0.w += v0.w;
            a1.x += v1.x; a1.y += v1.y; a1.z += v1.z; a1.w += v1.w;
            a0.x += v2.x; a0.y += v2.y; a0.z += v2.z; a0.w += v2.w;
            a1.x += v3.x; a1.y += v3.y; a1.z += v3.z; a1.w += v3.w;
            a0.x += v4.x; a0.y += v4.y; a0.z += v4.z; a0.w += v4.w;
            a1.x += v5.x; a1.y += v5.y; a1.z += v5.z; a1.w += v5.w;
            a0.x += v6.x; a0.y += v6.y; a0.z += v6.z; a0.w += v6.w;
            a1.x += v7.x; a1.y += v7.y; a1.z += v7.z; a1.w += v7.w;
        }
        for (; r < rend; ++r) {
            float4 v = src[r * D4 + col];
            a0.x += v.x; a0.y += v.y; a0.z += v.z; a0.w += v.w;
        }
        a0.x += a1.x; a0.y += a1.y; a0.z += a1.z; a0.w += a1.w;

        // Combine the two run halves; half 0 accumulates into out.
        if (half == 1) s_red[col] = a0;
        __syncthreads();
        if (half == 0) {
            float4 o = s_red[col];
            a0.x += o.x; a0.y += o.y; a0.z += o.z; a0.w += o.w;
            const float inv = 1.0f / (float)(s_ps[k + 1] - s_ps[k]);
            float* dst = out + k * D + col * 4;
            atomicAdd(dst + 0, a0.x * inv);
            atomicAdd(dst + 1, a0.y * inv);
            atomicAdd(dst + 2, a0.z * inv);
            atomicAdd(dst + 3, a0.w * inv);
        }
        __syncthreads();   // protect s_red before next segment reuses it
        cur = e;
        ++k;
    }
}

extern "C" void kernel_launch(void* const* d_in, const int* in_sizes, int n_in,
                              void* d_out, int out_size, void* d_ws, size_t ws_size,
                              hipStream_t stream) {
    const float* samples = (const float*)d_in[0];
    const int*   counts  = (const int*)d_in[1];   // harness converts int64 -> int32
    float*       out     = (float*)d_out;
    const int    tt      = in_sizes[0] / D;       // total rows (131072)

    // Zero the output accumulator (graph-capturable).
    hipMemsetAsync(out, 0, (size_t)out_size * sizeof(float), stream);
    agg_slab_kernel<<<NCH, 256, 0, stream>>>(samples, counts, out, tt);
}